// Round 11
// baseline (2769.187 us; speedup 1.0000x reference)
//
#include <hip/hip_runtime.h>
#include <stdint.h>
#include <stddef.h>

// Routed 2-cell LSTM, B=64, S=512, E=H=256.
// Phase 1 (xproj_kernel): precompute xg[t][g][b] = routed-cell W_ih·x_t + bias.
// Phase 2 (mlstm_rec_kernel, 32 persistent wgs): recurrence with EPOCH-IN-DWORD
//   h exchange at K-SLICE granularity: h value published as {bf16<<16|epoch16}
//   (aligned dword = single-copy atomic), producer-side LDS bounce -> coalesced
//   dwordx4 sc0 sc1 stores, fire-and-forget (NO ack, NO flags). Consumer polls
//   its OWN producer slice per K-chunk (16 dwords/lane), validates epochs,
//   retries that slice only, packs hi16 -> MFMA. Arrival-driven: early slices'
//   MFMAs overlap the wait for late ones. Update-ready MFMA row ordering
//   (round 9). Numerics identical to rounds 8-10.

#define BB   64
#define SS   512
#define EE   256
#define HH   256
#define G4   1024
#define NWG  32
#define TPB  512
#define TCH  32

typedef __attribute__((ext_vector_type(8))) short short8;
typedef __attribute__((ext_vector_type(4))) float f32x4;
typedef __attribute__((ext_vector_type(4))) unsigned int uint4v;

__device__ __forceinline__ unsigned short f2bf(float f){
  union { float f; unsigned u; } v; v.f = f;
  return (unsigned short)((v.u + 0x7fffu + ((v.u >> 16) & 1u)) >> 16);
}
__device__ __forceinline__ float bf2f(unsigned short s){
  union { float f; unsigned u; } v; v.u = ((unsigned)s) << 16;
  return v.f;
}

// ws layout (bytes):
// [1024, +131072)      : h dwords {bf16<<16|epoch}, 2 parities x 16384 dwords
//                        slice layout: [wg][b][jloc] (512 dwords per wg)
// [132096, +134217728) : xg[t=512][g=1024][b=64] fp32 (routed-cell gates)
#define WS_H_OFF  1024
#define WS_XG_OFF (1024 + 131072)

__global__ void zero_ws_kernel(int* ws){
  const int n = (WS_H_OFF + 131072) / 4;
  for (int i = blockIdx.x * blockDim.x + threadIdx.x; i < n; i += gridDim.x * blockDim.x)
    ws[i] = 0;
}

// ---------------- Phase 1: x-projection GEMM ----------------
__global__ __launch_bounds__(TPB, 1)
void xproj_kernel(const int* __restrict__ input, const int* __restrict__ assign,
                  const float* __restrict__ emb, const float* __restrict__ Wih,
                  const float* __restrict__ bih, const float* __restrict__ bhh,
                  float* __restrict__ xg)
{
  __shared__ __align__(16) unsigned short sXp[8][4][4][16][8];
  __shared__ int sTokP[TCH][64];
  __shared__ int sAsgP[TCH][64];

  const int tid  = threadIdx.x;
  const int lane = tid & 63;
  const int lg   = lane >> 4;
  const int lc   = lane & 15;
  const int wv   = tid >> 6;
  const int rowtile = blockIdx.x & 15;
  const int tc      = blockIdx.x >> 4;

  const int rbase = rowtile * 128 + wv * 16;
  const int cellw = rbase >> 10;
  const int rrw   = rbase & 1023;

  short8 aX[8];
  {
    const float* pw = Wih + ((size_t)cellw * G4 + (rrw + lc)) * EE + lg * 8;
    #pragma unroll
    for (int kc = 0; kc < 8; ++kc){
      const f32x4 u = *(const f32x4*)(pw + kc * 32);
      const f32x4 v = *(const f32x4*)(pw + kc * 32 + 4);
      short8 x8;
      #pragma unroll
      for (int e = 0; e < 4; ++e){ x8[e] = (short)f2bf(u[e]); x8[4+e] = (short)f2bf(v[e]); }
      aX[kc] = x8;
    }
  }
  float biasr[4];
  #pragma unroll
  for (int q = 0; q < 4; ++q){
    const int idx = cellw * G4 + rrw + lg * 4 + q;
    biasr[q] = bih[idx] + bhh[idx];
  }

  for (int i = tid; i < TCH * 64; i += TPB){
    const int tl = i >> 6, b = i & 63;
    const int tok = input[b * SS + tc * TCH + tl];
    sTokP[tl][b] = tok; sAsgP[tl][b] = assign[tok];
  }
  __syncthreads();

  const int gkc = tid >> 6, glg = (tid >> 4) & 3, glc = tid & 15;
  short8 xr[4];
  auto GATHERP = [&](int tl){
    #pragma unroll
    for (int ct = 0; ct < 4; ++ct){
      const int tok = sTokP[tl][ct * 16 + glc];
      const float* ep = emb + (size_t)tok * EE + gkc * 32 + glg * 8;
      const f32x4 u = *(const f32x4*)ep;
      const f32x4 v = *(const f32x4*)(ep + 4);
      short8 x8;
      #pragma unroll
      for (int e = 0; e < 4; ++e){ x8[e] = (short)f2bf(u[e]); x8[4+e] = (short)f2bf(v[e]); }
      xr[ct] = x8;
    }
  };
  GATHERP(0);

  for (int tl = 0; tl < TCH; ++tl){
    #pragma unroll
    for (int ct = 0; ct < 4; ++ct)
      *(short8*)&sXp[gkc][glg][ct][glc][0] = xr[ct];
    __syncthreads();
    if (tl + 1 < TCH) GATHERP(tl + 1);

    f32x4 acc[4];
    #pragma unroll
    for (int ct = 0; ct < 4; ++ct){
      acc[ct][0] = biasr[0]; acc[ct][1] = biasr[1];
      acc[ct][2] = biasr[2]; acc[ct][3] = biasr[3];
    }
    #pragma unroll
    for (int kc = 0; kc < 8; ++kc){
      #pragma unroll
      for (int ct = 0; ct < 4; ++ct){
        const short8 bx = *(const short8*)&sXp[kc][lg][ct][lc][0];
        acc[ct] = __builtin_amdgcn_mfma_f32_16x16x32_bf16(aX[kc], bx, acc[ct], 0, 0, 0);
      }
    }
    float* xgt = xg + (size_t)(tc * TCH + tl) * 65536;
    #pragma unroll
    for (int ct = 0; ct < 4; ++ct){
      const int b = ct * 16 + lc;
      if (sAsgP[tl][b] == cellw){
        #pragma unroll
        for (int q = 0; q < 4; ++q)
          xgt[(rrw + lg * 4 + q) * 64 + b] = acc[ct][q];
      }
    }
    __syncthreads();
  }
}

// ---------------- Phase 2: recurrence (epoch-in-dword K-slice exchange) ----------------
__global__ __launch_bounds__(TPB, 1)
void mlstm_rec_kernel(const int* __restrict__ input, const int* __restrict__ assign,
                      const float* __restrict__ Whh, float* __restrict__ out,
                      char* __restrict__ ws)
{
  __shared__ unsigned int sHout[64][8];   // 2 KB publish bounce {bf16<<16|epoch}
  __shared__ float sC[64][8];             // 2 KB c-state
  __shared__ int sAsg[3][64];

  const int tid  = threadIdx.x;
  const int lane = tid & 63;
  const int lg   = lane >> 4;
  const int lc   = lane & 15;
  const int wv   = tid >> 6;        // 0..7
  const int cell  = wv & 1;
  const int jhalf = (wv >> 1) & 1;
  const int th    = wv >> 2;        // token half
  const int wg    = blockIdx.x;     // owns j in [wg*8, wg*8+8)

  unsigned int* hbuf = (unsigned int*)(ws + WS_H_OFF);
  const float* xg = (const float*)(ws + WS_XG_OFF);

  // ---- Whh A-frags hi/lo, rows ordered m=(j_sub<<2)|gate (update-ready) ----
  short8 aHiH[8], aLoH[8];
  {
    const float* ph = Whh + ((size_t)cell * G4 + (lc & 3) * HH
                             + wg * 8 + jhalf * 4 + (lc >> 2)) * HH + lg * 8;
    #pragma unroll
    for (int kc = 0; kc < 8; ++kc){
      const f32x4 u = *(const f32x4*)(ph + kc * 32);
      const f32x4 v = *(const f32x4*)(ph + kc * 32 + 4);
      short8 hi, lo;
      #pragma unroll
      for (int e = 0; e < 4; ++e){
        const float w0 = u[e], w1 = v[e];
        const unsigned short h0 = f2bf(w0), h1 = f2bf(w1);
        hi[e] = (short)h0;   lo[e] = (short)f2bf(w0 - bf2f(h0));
        hi[4+e] = (short)h1; lo[4+e] = (short)f2bf(w1 - bf2f(h1));
      }
      aHiH[kc] = hi; aLoH[kc] = lo;
    }
  }

  if (tid < 64){
    const int t0 = input[tid * SS];     sAsg[0][tid] = assign[t0];
    const int t1 = input[tid * SS + 1]; sAsg[1][tid] = assign[t1];
  }

  const int jloc  = jhalf * 4 + lg;
  const int jglob = wg * 8 + jloc;

  float xpre[8];
  auto XPRE = [&](int t){
    const float* p = xg + (size_t)t * 65536 + jglob * 64 + th * 32 + lc;
    #pragma unroll
    for (int ct = 0; ct < 2; ++ct)
      #pragma unroll
      for (int q = 0; q < 4; ++q)
        xpre[ct * 4 + q] = p[q * 16384 + ct * 16];
  };
  XPRE(0);
  __syncthreads();

  for (int t = 0; t < SS; ++t){
    // ---- acc init from xg; prefetch next step + routing (overlaps polling) ----
    f32x4 acc[2];
    #pragma unroll
    for (int ct = 0; ct < 2; ++ct)
      #pragma unroll
      for (int q = 0; q < 4; ++q)
        acc[ct][q] = xpre[ct * 4 + q];
    if (t + 1 < SS) XPRE(t + 1);
    if (t + 2 < SS && tid < 64){
      const int tk = input[tid * SS + (t + 2)];
      sAsg[(t + 2) % 3][tid] = assign[tk];
    }

    // ---- h-part: per-K-slice validated load + MFMA (arrival-driven) ----
    if (t > 0){
      const unsigned int* hr = hbuf + (size_t)(t & 1) * 16384;
      const unsigned int need16 = (unsigned int)t;
      #pragma unroll
      for (int kch = 0; kch < 8; ++kch){
        // lane's B-frag j-range lives entirely in producer slice p = kch*4+lg
        const unsigned int* sl = hr + (kch * 4 + lg) * 512 + (th * 32 + lc) * 8;
        uint4v A0, A1, B0, B1;
        while (true){
          asm volatile("global_load_dwordx4 %0, %1, off sc0 sc1" : "=v"(A0) : "v"(sl)       : "memory");
          asm volatile("global_load_dwordx4 %0, %1, off sc0 sc1" : "=v"(A1) : "v"(sl + 4)   : "memory");
          asm volatile("global_load_dwordx4 %0, %1, off sc0 sc1" : "=v"(B0) : "v"(sl + 128) : "memory");
          asm volatile("global_load_dwordx4 %0, %1, off sc0 sc1" : "=v"(B1) : "v"(sl + 132) : "memory");
          asm volatile("s_waitcnt vmcnt(0)" ::: "memory");
          unsigned bad = 0;
          #pragma unroll
          for (int e = 0; e < 4; ++e){
            bad |= (A0[e] ^ need16); bad |= (A1[e] ^ need16);
            bad |= (B0[e] ^ need16); bad |= (B1[e] ^ need16);
          }
          bad &= 0xFFFFu;
          if (__ballot(bad != 0) == 0ull) break;
        }
        short8 hh0, hh1;
        {
          unsigned* w0 = (unsigned*)&hh0;
          unsigned* w1 = (unsigned*)&hh1;
          w0[0] = (A0[0] >> 16) | (A0[1] & 0xFFFF0000u);
          w0[1] = (A0[2] >> 16) | (A0[3] & 0xFFFF0000u);
          w0[2] = (A1[0] >> 16) | (A1[1] & 0xFFFF0000u);
          w0[3] = (A1[2] >> 16) | (A1[3] & 0xFFFF0000u);
          w1[0] = (B0[0] >> 16) | (B0[1] & 0xFFFF0000u);
          w1[1] = (B0[2] >> 16) | (B0[3] & 0xFFFF0000u);
          w1[2] = (B1[0] >> 16) | (B1[1] & 0xFFFF0000u);
          w1[3] = (B1[2] >> 16) | (B1[3] & 0xFFFF0000u);
        }
        acc[0] = __builtin_amdgcn_mfma_f32_16x16x32_bf16(aHiH[kch], hh0, acc[0], 0, 0, 0);
        acc[1] = __builtin_amdgcn_mfma_f32_16x16x32_bf16(aHiH[kch], hh1, acc[1], 0, 0, 0);
        acc[0] = __builtin_amdgcn_mfma_f32_16x16x32_bf16(aLoH[kch], hh0, acc[0], 0, 0, 0);
        acc[1] = __builtin_amdgcn_mfma_f32_16x16x32_bf16(aLoH[kch], hh1, acc[1], 0, 0, 0);
      }
    }

    // ---- in-register pointwise update: lane has {i,f,g,o} for (jglob, token) ----
    #pragma unroll
    for (int ct = 0; ct < 2; ++ct){
      const int b = th * 32 + ct * 16 + lc;
      const int a = sAsg[t % 3][b];
      if (a == cell){
        const float gi = acc[ct][0], gf = acc[ct][1];
        const float gg = acc[ct][2], go = acc[ct][3];
        const float cold = (t == 0) ? 0.f : sC[b][jloc];
        const float si = 1.f / (1.f + __expf(-gi));
        const float sf = 1.f / (1.f + __expf(-gf));
        const float so = 1.f / (1.f + __expf(-go));
        const float cn = sf * cold + si * tanhf(gg);
        const float hn = so * tanhf(cn);
        if (t < SS - 1){
          sC[b][jloc] = cn;
          sHout[b][jloc] = ((unsigned int)f2bf(hn) << 16) | ((unsigned int)(t + 1) & 0xFFFFu);
        } else {
          out[b * 512 + jglob]       = hn;
          out[b * 512 + 256 + jglob] = cn;
        }
      }
    }

    // ---- publish: coalesced dwordx4 copy-out, fire-and-forget (no ack, no flag) ----
    if (t < SS - 1){
      __syncthreads();           // sHout complete (also orders sC for next step)
      if (tid < 128){
        const uint4v v = *(const uint4v*)&((const unsigned int*)sHout)[tid * 4];
        unsigned int* dst = hbuf + (size_t)((t & 1) ^ 1) * 16384 + wg * 512 + tid * 4;
        asm volatile("global_store_dwordx4 %0, %1, off sc0 sc1" :: "v"(dst), "v"(v) : "memory");
      }
      // no wait: next-step consumers validate epochs directly.
      // Self-sync: our own next-step sHout writes can't start until our copy-out
      // data is visible (consumers gate on it), so no intra-wg WAR hazard.
    }
  }
}

extern "C" void kernel_launch(void* const* d_in, const int* in_sizes, int n_in,
                              void* d_out, int out_size, void* d_ws, size_t ws_size,
                              hipStream_t stream)
{
  const int*   input  = (const int*)  d_in[0];
  const int*   assign = (const int*)  d_in[1];
  const float* emb    = (const float*)d_in[2];
  const float* Wih    = (const float*)d_in[3];
  const float* Whh    = (const float*)d_in[4];
  const float* bih    = (const float*)d_in[5];
  const float* bhh    = (const float*)d_in[6];
  float* out = (float*)d_out;
  char*  ws  = (char*)d_ws;

  zero_ws_kernel<<<64, 256, 0, stream>>>((int*)ws);
  float* xg = (float*)(ws + WS_XG_OFF);
  xproj_kernel<<<256, TPB, 0, stream>>>(input, assign, emb, Wih, bih, bhh, xg);
  mlstm_rec_kernel<<<NWG, TPB, 0, stream>>>(input, assign, Whh, out, ws);
}